// Round 14
// baseline (1576.009 us; speedup 1.0000x reference)
//
#include <hip/hip_runtime.h>
#include <hip/hip_bf16.h>
#include <math.h>

constexpr int N_NODES = 50000;
constexpr int HD = 64;
constexpr int NBKT = (N_NODES + 255) / 256;   // 196 buckets of 256 nodes

typedef float floatx2 __attribute__((ext_vector_type(2)));

__device__ __forceinline__ float bf2f(unsigned short u) {
    return __uint_as_float((unsigned)u << 16);
}
__device__ __forceinline__ unsigned short f2bf(float f) {
    __hip_bfloat16 b = __float2bfloat16(f);
    return *(unsigned short*)&b;
}
__device__ __forceinline__ unsigned pack_fp8x4(float a, float b, float c, float d) {
    unsigned p = __builtin_amdgcn_cvt_pk_fp8_f32(a, b, 0u, false);
    return __builtin_amdgcn_cvt_pk_fp8_f32(c, d, p, true);
}
__device__ __forceinline__ float dot16_fp8(uint4 u, uint4 d) {
    const unsigned uu[4] = {u.x, u.y, u.z, u.w};
    const unsigned dd[4] = {d.x, d.y, d.z, d.w};
    float s = 0.f;
#pragma unroll
    for (int q = 0; q < 4; ++q) {
        floatx2 ua = __builtin_amdgcn_cvt_pk_f32_fp8(uu[q], false);
        floatx2 ub = __builtin_amdgcn_cvt_pk_f32_fp8(uu[q], true);
        floatx2 da = __builtin_amdgcn_cvt_pk_f32_fp8(dd[q], false);
        floatx2 db = __builtin_amdgcn_cvt_pk_f32_fp8(dd[q], true);
        s = fmaf(ua[0], da[0], s);
        s = fmaf(ua[1], da[1], s);
        s = fmaf(ub[0], db[0], s);
        s = fmaf(ub[1], db[1], s);
    }
    return s;
}

// ---------- A: bucket histogram (LDS-staged) ----------
__global__ __launch_bounds__(256) void bhist_kernel(const int* __restrict__ dst,
                                                    int* __restrict__ bcnt, int E) {
    __shared__ int lh[256];
    const int t = threadIdx.x;
    lh[t] = 0;
    __syncthreads();
    const int beg = blockIdx.x * 2048;
    const int end = min(beg + 2048, E);
    for (int i = beg + t; i < end; i += 256)
        atomicAdd(&lh[dst[i] >> 8], 1);
    __syncthreads();
    if (t < NBKT && lh[t]) atomicAdd(&bcnt[t], lh[t]);
}

// ---------- B: scan bucket counts -> bbase, init gcur ----------
__global__ __launch_bounds__(256) void bscan_kernel(const int* __restrict__ bcnt,
                                                    int* __restrict__ bbase,
                                                    int* __restrict__ gcur) {
    const int t = threadIdx.x;
    const int v = (t < NBKT) ? bcnt[t] : 0;
    const int lane = t & 63, wid = t >> 6;
    int incl = v;
#pragma unroll
    for (int o = 1; o <= 32; o <<= 1) {
        int u = __shfl_up(incl, o);
        if (lane >= o) incl += u;
    }
    __shared__ int wt[4];
    if (lane == 63) wt[wid] = incl;
    __syncthreads();
    int base = 0;
    for (int w = 0; w < wid; ++w) base += wt[w];
    const int excl = base + incl - v;
    if (t < NBKT) { bbase[t] = excl; gcur[t] = excl; }
    if (t == NBKT - 1) bbase[NBKT] = excl + v;
}

// ---------- C: partition edges into bucket-grouped pk ----------
__global__ __launch_bounds__(256) void partition_kernel(const int* __restrict__ src,
                                                        const int* __restrict__ dst,
                                                        int* __restrict__ gcur,
                                                        unsigned* __restrict__ pk, int E) {
    __shared__ unsigned epk[8192];
    __shared__ int lh[NBKT], lbase[NBKT], lcur[NBKT];
    const int t = threadIdx.x;
    for (int i = t; i < NBKT; i += 256) { lh[i] = 0; lcur[i] = 0; }
    __syncthreads();
    const int beg = blockIdx.x * 8192;
    const int end = min(beg + 8192, E);
    for (int i = beg + t; i < end; i += 256) {
        const int s = src[i], d = dst[i];
        const int bkt = d >> 8;
        epk[i - beg] = ((unsigned)bkt << 24) | ((unsigned)(d & 255) << 16) | (unsigned)s;
        atomicAdd(&lh[bkt], 1);
    }
    __syncthreads();
    for (int i = t; i < NBKT; i += 256)
        if (lh[i]) lbase[i] = atomicAdd(&gcur[i], lh[i]);
    __syncthreads();
    for (int i = beg + t; i < end; i += 256) {
        const unsigned p = epk[i - beg];
        const int bkt = p >> 24;
        const int r = atomicAdd(&lcur[bkt], 1);
        pk[lbase[bkt] + r] = p;
    }
}

// ---------- D: per-bucket counting sort -> csr32 ((dloc<<16)|src), off, dis ----------
__global__ __launch_bounds__(256) void bsort_kernel(const unsigned* __restrict__ pk,
                                                    const int* __restrict__ bbase,
                                                    int* __restrict__ off,
                                                    float* __restrict__ dis,
                                                    unsigned* __restrict__ csr, int E, int N) {
    __shared__ int ncnt[256], nbs[256], ncur[256];
    __shared__ int wt[4];
    const int t = threadIdx.x;
    const int bkt = blockIdx.x;
    const int gb = bbase[bkt], ge = bbase[bkt + 1];
    ncnt[t] = 0; ncur[t] = 0;
    __syncthreads();
    for (int i = gb + t; i < ge; i += 256)
        atomicAdd(&ncnt[(pk[i] >> 16) & 255], 1);
    __syncthreads();
    const int v = ncnt[t];
    const int lane = t & 63, wid = t >> 6;
    int incl = v;
#pragma unroll
    for (int o = 1; o <= 32; o <<= 1) {
        int u = __shfl_up(incl, o);
        if (lane >= o) incl += u;
    }
    if (lane == 63) wt[wid] = incl;
    __syncthreads();
    int base = 0;
    for (int w = 0; w < wid; ++w) base += wt[w];
    nbs[t] = base + incl - v;
    const int n = bkt * 256 + t;
    if (n < N) {
        off[n] = gb + nbs[t];
        dis[n] = rsqrtf((float)v + 1.0f);
        if (n == N - 1) off[N] = E;
    }
    __syncthreads();
    for (int i = gb + t; i < ge; i += 256) {
        const unsigned p = pk[i];
        const int dl = (p >> 16) & 255;
        const int r = atomicAdd(&ncur[dl], 1);
        csr[gb + nbs[dl] + r] = p & 0x00FFFFFFu;   // (dloc<<16)|src
    }
}

// ---------- GEMM: LDS-tiled 64x64, 4x4 micro-tile; emits pre-scaled fp8 hs ----------
template <int K, bool INBF16>
__global__ __launch_bounds__(256) void gemm_kernel(const void* __restrict__ in_,
                                                   const float* __restrict__ W,
                                                   const float* __restrict__ dis,
                                                   unsigned* __restrict__ out8, int N) {
    __shared__ float xs[64][68];
    __shared__ float Wl[64][64];
    const int t = threadIdx.x;
    const int row0 = blockIdx.x * 64;
    const int cq = t & 15, rq = t >> 4;
    float acc[4][4] = {{0.f}};
    for (int kc = 0; kc < K; kc += 64) {
#pragma unroll
        for (int it = 0; it < 4; ++it) {
            const int idx = it * 256 + t;
            const int r = idx >> 4, c4 = idx & 15;
            const int rr = min(row0 + r, N - 1);
            if constexpr (INBF16) {
                const unsigned short* in16 = (const unsigned short*)in_;
                const ushort4 v = *(const ushort4*)(in16 + (size_t)rr * K + kc + c4 * 4);
                *(float4*)(&xs[r][c4 * 4]) = make_float4(bf2f(v.x), bf2f(v.y), bf2f(v.z), bf2f(v.w));
            } else {
                const float* inf = (const float*)in_;
                *(float4*)(&xs[r][c4 * 4]) = *(const float4*)(inf + (size_t)rr * K + kc + c4 * 4);
            }
            *(float4*)(&Wl[r][c4 * 4]) = *(const float4*)(W + (size_t)(kc + r) * HD + c4 * 4);
        }
        __syncthreads();
#pragma unroll
        for (int k4 = 0; k4 < 16; ++k4) {
            float a[4][4], b[4][4];
#pragma unroll
            for (int i = 0; i < 4; ++i)
                *(float4*)a[i] = *(const float4*)(&xs[rq * 4 + i][k4 * 4]);
#pragma unroll
            for (int kk = 0; kk < 4; ++kk)
                *(float4*)b[kk] = *(const float4*)(&Wl[k4 * 4 + kk][cq * 4]);
#pragma unroll
            for (int kk = 0; kk < 4; ++kk)
#pragma unroll
                for (int i = 0; i < 4; ++i)
#pragma unroll
                    for (int j = 0; j < 4; ++j)
                        acc[i][j] = fmaf(a[i][kk], b[kk][j], acc[i][j]);
        }
        __syncthreads();
    }
#pragma unroll
    for (int i = 0; i < 4; ++i) {
        const int r = row0 + rq * 4 + i;
        if (r < N) {
            const float dr = dis[r];
            out8[(size_t)r * 16 + cq] =
                pack_fp8x4(acc[i][0] * dr, acc[i][1] * dr, acc[i][2] * dr, acc[i][3] * dr);
        }
    }
}

// ---------- edge-parallel aggregation: one block per 64-node window ----------
// LDS accumulators accsm[64][65] (stride 65 -> bank = (dloc+h)&31, spread).
// 8-lane groups stream contiguous edges: gather 64B of hs[src], 8 cvt, 8 ds_add.
// Epilogue: out = relu(dn*(accsm + hs[n]) + b), bf16 write.
__global__ __launch_bounds__(256) void agg_kernel(const unsigned* __restrict__ csr,
                                                  const int* __restrict__ off,
                                                  const float* __restrict__ dis,
                                                  const unsigned* __restrict__ hs,
                                                  const float* __restrict__ b,
                                                  unsigned short* __restrict__ z16, int N) {
    __shared__ float accsm[64][65];
    const int t = threadIdx.x;
    const int n0 = blockIdx.x * 64;
    if (n0 >= N) return;
    const int nEnd = min(n0 + 64, N);
    const int beg = off[n0], end = off[nEnd];
    for (int i = t; i < 64 * 65; i += 256) ((float*)accsm)[i] = 0.f;
    __syncthreads();

    const int g = t >> 3, p = t & 7;        // 32 edge groups x 8 lanes
    int i = beg + g;
    unsigned e = 0;
    uint2 hv;
    bool valid = i < end;
    if (valid) {
        e  = csr[i];
        hv = *(const uint2*)(hs + (size_t)(e & 0xFFFFu) * 16 + p * 2);
    }
    while (valid) {
        const int inx = i + 32;
        const bool vn = inx < end;
        unsigned en = 0;
        uint2 nv;
        if (vn) {
            en = csr[inx];
            nv = *(const uint2*)(hs + (size_t)(en & 0xFFFFu) * 16 + p * 2);
        }
        const int dl = (e >> 16) & 63;
        float* row = accsm[dl];
        floatx2 f01 = __builtin_amdgcn_cvt_pk_f32_fp8(hv.x, false);
        floatx2 f23 = __builtin_amdgcn_cvt_pk_f32_fp8(hv.x, true);
        floatx2 f45 = __builtin_amdgcn_cvt_pk_f32_fp8(hv.y, false);
        floatx2 f67 = __builtin_amdgcn_cvt_pk_f32_fp8(hv.y, true);
        atomicAdd(&row[p * 8 + 0], f01[0]);
        atomicAdd(&row[p * 8 + 1], f01[1]);
        atomicAdd(&row[p * 8 + 2], f23[0]);
        atomicAdd(&row[p * 8 + 3], f23[1]);
        atomicAdd(&row[p * 8 + 4], f45[0]);
        atomicAdd(&row[p * 8 + 5], f45[1]);
        atomicAdd(&row[p * 8 + 6], f67[0]);
        atomicAdd(&row[p * 8 + 7], f67[1]);
        i = inx; e = en; hv = nv; valid = vn;
    }
    __syncthreads();

    // epilogue: thread t -> node n0 + t/4, h-quad (t&3)*16
    const int nl = t >> 2, hb = (t & 3) * 16;
    const int n = n0 + nl;
    if (n < N) {
        const float dn = dis[n];
        const uint4 sv = *(const uint4*)(hs + (size_t)n * 16 + (hb >> 2));
        const unsigned ss[4] = {sv.x, sv.y, sv.z, sv.w};
        float o[16];
#pragma unroll
        for (int q = 0; q < 4; ++q) {
            floatx2 lo = __builtin_amdgcn_cvt_pk_f32_fp8(ss[q], false);
            floatx2 hi = __builtin_amdgcn_cvt_pk_f32_fp8(ss[q], true);
            o[4 * q + 0] = lo[0]; o[4 * q + 1] = lo[1];
            o[4 * q + 2] = hi[0]; o[4 * q + 3] = hi[1];
        }
        const float* bb = b + hb;
        ushort4 w[4];
#pragma unroll
        for (int j = 0; j < 16; ++j) {
            const float v = fmaxf(fmaf(accsm[nl][hb + j] + o[j], dn, bb[j]), 0.f);
            ((unsigned short*)w)[j] = f2bf(v);
        }
        unsigned short* zp = z16 + (size_t)n * HD + hb;
#pragma unroll
        for (int q = 0; q < 4; ++q) *(ushort4*)(zp + q * 4) = w[q];
    }
}

// ---------- u/d precompute -> fp8 ----------
__global__ __launch_bounds__(256) void uprep_kernel(const unsigned short* __restrict__ z16,
                                                    const float* __restrict__ Wp,
                                                    unsigned* __restrict__ u8,
                                                    unsigned* __restrict__ d8, int N) {
    const int i = blockIdx.x * blockDim.x + threadIdx.x;
    const int total = N * HD;
    if (i >= total) return;
    const size_t NH = (size_t)N_NODES * HD;
    const float z0 = bf2f(z16[0 * NH + i]), z1 = bf2f(z16[1 * NH + i]);
    const float z2 = bf2f(z16[2 * NH + i]), z3 = bf2f(z16[3 * NH + i]);
    d8[i] = pack_fp8x4(z0, z1, z2, z3);
    const float u0 = z0 * Wp[0] + z1 * Wp[4] + z2 * Wp[8]  + z3 * Wp[12];
    const float u1 = z0 * Wp[1] + z1 * Wp[5] + z2 * Wp[9]  + z3 * Wp[13];
    const float u2 = z0 * Wp[2] + z1 * Wp[6] + z2 * Wp[10] + z3 * Wp[14];
    const float u3 = z0 * Wp[3] + z1 * Wp[7] + z2 * Wp[11] + z3 * Wp[15];
    u8[i] = pack_fp8x4(u0, u1, u2, u3);
}

// ---------- link prediction + BCE loss: 16-lane groups, 8 edges / wave-iter ----------
__global__ __launch_bounds__(256) void linkpred_kernel(const unsigned* __restrict__ u8,
                                                       const unsigned* __restrict__ d8,
                                                       const int* __restrict__ pos,
                                                       const int* __restrict__ neg,
                                                       const float* __restrict__ bp,
                                                       double* __restrict__ acc, int EP) {
    const int lane = threadIdx.x & 63;
    const int wid  = threadIdx.x >> 6;
    const int grp  = lane >> 4;
    const int p    = lane & 15;
    const float bpv = bp[0];
    int gw = blockIdx.x * 4 + wid;
    const int nw = gridDim.x * 4;
    const int nchunks = (2 * EP) >> 3;
    float lsum = 0.f;
    for (int c0 = gw; c0 < nchunks; c0 += nw) {
        const int c = __builtin_amdgcn_readfirstlane(c0);
        const int i0 = c << 3;
        const bool is_pos = i0 < EP;
        const int* __restrict__ eptr = is_pos ? pos : neg;
        const int jj0 = is_pos ? i0 : i0 - EP;
        int idx = 0;
        if (lane < 16)
            idx = (lane < 8) ? eptr[jj0 + lane] : eptr[EP + jj0 + lane - 8];
        const int e0a = __shfl(idx, grp),     e1a = __shfl(idx, 8 + grp);
        const int e0b = __shfl(idx, 4 + grp), e1b = __shfl(idx, 12 + grp);
        const uint4 ua = *(const uint4*)(u8 + (size_t)e0a * HD + p * 4);
        const uint4 da = *(const uint4*)(d8 + (size_t)e1a * HD + p * 4);
        const uint4 ub = *(const uint4*)(u8 + (size_t)e0b * HD + p * 4);
        const uint4 db = *(const uint4*)(d8 + (size_t)e1b * HD + p * 4);
        float tA = dot16_fp8(ua, da);
        float tB = dot16_fp8(ub, db);
#pragma unroll
        for (int st = 1; st <= 8; st <<= 1) {
            tA += __shfl_xor(tA, st);
            tB += __shfl_xor(tB, st);
        }
        const float ga = __shfl(tA, (lane & 3) * 16);
        const float gb = __shfl(tB, (lane & 3) * 16);
        const float tt = (lane < 4) ? ga : gb;
        if (lane < 8) {
            float logit  = tt + bpv;
            float target = (i0 + lane == EP) ? 1.f : 0.f;
            lsum += fmaxf(logit, 0.f) - logit * target + log1pf(expf(-fabsf(logit)));
        }
    }
#pragma unroll
    for (int o = 32; o >= 1; o >>= 1) lsum += __shfl_xor(lsum, o);
    __shared__ float wsum[4];
    if (lane == 0) wsum[wid] = lsum;
    __syncthreads();
    if (threadIdx.x == 0) {
        double bs = (double)wsum[0] + (double)wsum[1] + (double)wsum[2] + (double)wsum[3];
        atomicAdd(acc, bs);
    }
}

__global__ void loss_final(const double* __restrict__ acc, float* __restrict__ out, int denom) {
    out[0] = (float)(acc[0] / (double)denom);
}

extern "C" void kernel_launch(void* const* d_in, const int* in_sizes, int n_in,
                              void* d_out, int out_size, void* d_ws, size_t ws_size,
                              hipStream_t stream) {
    const float* x   = (const float*)d_in[0];
    const int*   ei  = (const int*)d_in[1];
    const int*   pos = (const int*)d_in[2];
    const int*   neg = (const int*)d_in[3];
    const float* W0  = (const float*)d_in[4];
    const float* b0  = (const float*)d_in[5];
    const float* Wh  = (const float*)d_in[6];
    const float* bh  = (const float*)d_in[7];
    const float* Wp  = (const float*)d_in[8];
    const float* bp  = (const float*)d_in[9];
    const int E  = in_sizes[1] / 2;   // 800000
    const int EP = in_sizes[2] / 2;   // 100000
    const int N  = N_NODES;
    const size_t NH = (size_t)N * HD;

    // ---- workspace layout (256B aligned) ----
    char* ws = (char*)d_ws;
    size_t off_b = 0;
    auto alloc = [&](size_t bytes) { char* p = ws + off_b; off_b = (off_b + bytes + 255) & ~(size_t)255; return p; };
    unsigned*       hs  = (unsigned*)alloc((size_t)N * 16 * sizeof(unsigned));       // 3.2 MB
    unsigned short* z16 = (unsigned short*)alloc(4 * NH * sizeof(unsigned short));   // 25.6 MB
    unsigned*       u8  = (unsigned*)alloc(NH * sizeof(unsigned));                   // 12.8 MB
    unsigned*       d8  = (unsigned*)alloc(NH * sizeof(unsigned));                   // 12.8 MB
    float* dis = (float*)alloc((size_t)N * sizeof(float));                           // 200 KB
    int*   off = (int*)alloc((size_t)(N + 1) * sizeof(int));                         // 200 KB
    unsigned* csr = (unsigned*)alloc((size_t)E * sizeof(unsigned));                  // 3.2 MB
    unsigned* pk  = (unsigned*)alloc((size_t)E * sizeof(unsigned));                  // 3.2 MB
    int*   bbase = (int*)alloc((size_t)(NBKT + 1) * sizeof(int));
    int*   gcur  = (int*)alloc((size_t)NBKT * sizeof(int));
    char*  zbase = ws + off_b;
    int*   bcnt = (int*)alloc((size_t)NBKT * sizeof(int));
    double* acc = (double*)alloc(sizeof(double));
    size_t zero_bytes = (size_t)((char*)acc - zbase) + sizeof(double);

    hipMemsetAsync(zbase, 0, zero_bytes, stream);

    const int* src = ei;
    const int* dst = ei + E;

    // CSR build: bucket hist -> scan -> partition -> per-bucket sort (+off, dis)
    bhist_kernel<<<(E + 2047) / 2048, 256, 0, stream>>>(dst, bcnt, E);
    bscan_kernel<<<1, 256, 0, stream>>>(bcnt, bbase, gcur);
    partition_kernel<<<(E + 8191) / 8192, 256, 0, stream>>>(src, dst, gcur, pk, E);
    bsort_kernel<<<NBKT, 256, 0, stream>>>(pk, bbase, off, dis, csr, E, N);

    const int agg_blocks  = (N + 63) / 64;   // 782: one block per 64-node window
    const int gemm_blocks = (N + 63) / 64;

    // layer 0
    gemm_kernel<128, false><<<gemm_blocks, 256, 0, stream>>>(x, W0, dis, hs, N);
    agg_kernel<<<agg_blocks, 256, 0, stream>>>(csr, off, dis, hs, b0, z16, N);

    // layers 1..3
    for (int l = 1; l < 4; ++l) {
        unsigned short* zprev = z16 + (size_t)(l - 1) * NH;
        unsigned short* zcur  = z16 + (size_t)l * NH;
        gemm_kernel<64, true><<<gemm_blocks, 256, 0, stream>>>(zprev, Wh + (size_t)(l - 1) * HD * HD, dis, hs, N);
        agg_kernel<<<agg_blocks, 256, 0, stream>>>(csr, off, dis, hs,
                                                   bh + (size_t)(l - 1) * HD, zcur, N);
    }

    // link prediction + loss
    uprep_kernel<<<(N * HD + 255) / 256, 256, 0, stream>>>(z16, Wp, u8, d8, N);
    linkpred_kernel<<<2048, 256, 0, stream>>>(u8, d8, pos, neg, bp, acc, EP);
    loss_final<<<1, 1, 0, stream>>>(acc, (float*)d_out, 2 * EP);
}

// Round 15
// 275.807 us; speedup vs baseline: 5.7142x; 5.7142x over previous
//
#include <hip/hip_runtime.h>
#include <hip/hip_bf16.h>
#include <math.h>

constexpr int N_NODES = 50000;
constexpr int HD = 64;
constexpr int NBKT = (N_NODES + 255) / 256;   // 196 buckets of 256 nodes

typedef float floatx2 __attribute__((ext_vector_type(2)));

__device__ __forceinline__ float bf2f(unsigned short u) {
    return __uint_as_float((unsigned)u << 16);
}
__device__ __forceinline__ unsigned short f2bf(float f) {
    __hip_bfloat16 b = __float2bfloat16(f);
    return *(unsigned short*)&b;
}
__device__ __forceinline__ unsigned pack_fp8x4(float a, float b, float c, float d) {
    unsigned p = __builtin_amdgcn_cvt_pk_fp8_f32(a, b, 0u, false);
    return __builtin_amdgcn_cvt_pk_fp8_f32(c, d, p, true);
}

// ---------- A: bucket histogram (LDS-staged) ----------
__global__ __launch_bounds__(256) void bhist_kernel(const int* __restrict__ dst,
                                                    int* __restrict__ bcnt, int E) {
    __shared__ int lh[256];
    const int t = threadIdx.x;
    lh[t] = 0;
    __syncthreads();
    const int beg = blockIdx.x * 2048;
    const int end = min(beg + 2048, E);
    for (int i = beg + t; i < end; i += 256)
        atomicAdd(&lh[dst[i] >> 8], 1);
    __syncthreads();
    if (t < NBKT && lh[t]) atomicAdd(&bcnt[t], lh[t]);
}

// ---------- B: scan bucket counts -> bbase, init gcur ----------
__global__ __launch_bounds__(256) void bscan_kernel(const int* __restrict__ bcnt,
                                                    int* __restrict__ bbase,
                                                    int* __restrict__ gcur) {
    const int t = threadIdx.x;
    const int v = (t < NBKT) ? bcnt[t] : 0;
    const int lane = t & 63, wid = t >> 6;
    int incl = v;
#pragma unroll
    for (int o = 1; o <= 32; o <<= 1) {
        int u = __shfl_up(incl, o);
        if (lane >= o) incl += u;
    }
    __shared__ int wt[4];
    if (lane == 63) wt[wid] = incl;
    __syncthreads();
    int base = 0;
    for (int w = 0; w < wid; ++w) base += wt[w];
    const int excl = base + incl - v;
    if (t < NBKT) { bbase[t] = excl; gcur[t] = excl; }
    if (t == NBKT - 1) bbase[NBKT] = excl + v;
}

// ---------- C: partition edges into bucket-grouped pk ----------
__global__ __launch_bounds__(256) void partition_kernel(const int* __restrict__ src,
                                                        const int* __restrict__ dst,
                                                        int* __restrict__ gcur,
                                                        unsigned* __restrict__ pk, int E) {
    __shared__ unsigned epk[8192];
    __shared__ int lh[NBKT], lbase[NBKT], lcur[NBKT];
    const int t = threadIdx.x;
    for (int i = t; i < NBKT; i += 256) { lh[i] = 0; lcur[i] = 0; }
    __syncthreads();
    const int beg = blockIdx.x * 8192;
    const int end = min(beg + 8192, E);
    for (int i = beg + t; i < end; i += 256) {
        const int s = src[i], d = dst[i];
        const int bkt = d >> 8;
        epk[i - beg] = ((unsigned)bkt << 24) | ((unsigned)(d & 255) << 16) | (unsigned)s;
        atomicAdd(&lh[bkt], 1);
    }
    __syncthreads();
    for (int i = t; i < NBKT; i += 256)
        if (lh[i]) lbase[i] = atomicAdd(&gcur[i], lh[i]);
    __syncthreads();
    for (int i = beg + t; i < end; i += 256) {
        const unsigned p = epk[i - beg];
        const int bkt = p >> 24;
        const int r = atomicAdd(&lcur[bkt], 1);
        pk[lbase[bkt] + r] = p;
    }
}

// ---------- D: per-bucket counting sort -> csr, off, dis ----------
__global__ __launch_bounds__(256) void bsort_kernel(const unsigned* __restrict__ pk,
                                                    const int* __restrict__ bbase,
                                                    int* __restrict__ off,
                                                    float* __restrict__ dis,
                                                    int* __restrict__ csr, int E, int N) {
    __shared__ int ncnt[256], nbs[256], ncur[256];
    __shared__ int wt[4];
    const int t = threadIdx.x;
    const int bkt = blockIdx.x;
    const int gb = bbase[bkt], ge = bbase[bkt + 1];
    ncnt[t] = 0; ncur[t] = 0;
    __syncthreads();
    for (int i = gb + t; i < ge; i += 256)
        atomicAdd(&ncnt[(pk[i] >> 16) & 255], 1);
    __syncthreads();
    const int v = ncnt[t];
    const int lane = t & 63, wid = t >> 6;
    int incl = v;
#pragma unroll
    for (int o = 1; o <= 32; o <<= 1) {
        int u = __shfl_up(incl, o);
        if (lane >= o) incl += u;
    }
    if (lane == 63) wt[wid] = incl;
    __syncthreads();
    int base = 0;
    for (int w = 0; w < wid; ++w) base += wt[w];
    nbs[t] = base + incl - v;
    const int n = bkt * 256 + t;
    if (n < N) {
        off[n] = gb + nbs[t];
        dis[n] = rsqrtf((float)v + 1.0f);
        if (n == N - 1) off[N] = E;
    }
    __syncthreads();
    for (int i = gb + t; i < ge; i += 256) {
        const unsigned p = pk[i];
        const int dl = (p >> 16) & 255;
        const int r = atomicAdd(&ncur[dl], 1);
        csr[gb + nbs[dl] + r] = (int)(p & 0xFFFFu);
    }
}

// ---------- GEMM: LDS-tiled 64x64, 4x4 micro-tile; emits bf16 h16 + fp8 h8 ----------
template <int K, bool INBF16>
__global__ __launch_bounds__(256) void gemm_kernel(const void* __restrict__ in_,
                                                   const float* __restrict__ W,
                                                   unsigned short* __restrict__ out16,
                                                   unsigned* __restrict__ out8, int N) {
    __shared__ float xs[64][68];
    __shared__ float Wl[64][64];
    const int t = threadIdx.x;
    const int row0 = blockIdx.x * 64;
    const int cq = t & 15, rq = t >> 4;
    float acc[4][4] = {{0.f}};
    for (int kc = 0; kc < K; kc += 64) {
#pragma unroll
        for (int it = 0; it < 4; ++it) {
            const int idx = it * 256 + t;
            const int r = idx >> 4, c4 = idx & 15;
            const int rr = min(row0 + r, N - 1);
            if constexpr (INBF16) {
                const unsigned short* in16 = (const unsigned short*)in_;
                const ushort4 v = *(const ushort4*)(in16 + (size_t)rr * K + kc + c4 * 4);
                *(float4*)(&xs[r][c4 * 4]) = make_float4(bf2f(v.x), bf2f(v.y), bf2f(v.z), bf2f(v.w));
            } else {
                const float* inf = (const float*)in_;
                *(float4*)(&xs[r][c4 * 4]) = *(const float4*)(inf + (size_t)rr * K + kc + c4 * 4);
            }
            *(float4*)(&Wl[r][c4 * 4]) = *(const float4*)(W + (size_t)(kc + r) * HD + c4 * 4);
        }
        __syncthreads();
#pragma unroll
        for (int k4 = 0; k4 < 16; ++k4) {
            float a[4][4], b[4][4];
#pragma unroll
            for (int i = 0; i < 4; ++i)
                *(float4*)a[i] = *(const float4*)(&xs[rq * 4 + i][k4 * 4]);
#pragma unroll
            for (int kk = 0; kk < 4; ++kk)
                *(float4*)b[kk] = *(const float4*)(&Wl[k4 * 4 + kk][cq * 4]);
#pragma unroll
            for (int kk = 0; kk < 4; ++kk)
#pragma unroll
                for (int i = 0; i < 4; ++i)
#pragma unroll
                    for (int j = 0; j < 4; ++j)
                        acc[i][j] = fmaf(a[i][kk], b[kk][j], acc[i][j]);
        }
        __syncthreads();
    }
#pragma unroll
    for (int i = 0; i < 4; ++i) {
        const int r = row0 + rq * 4 + i;
        if (r < N) {
            ushort4 o;
            o.x = f2bf(acc[i][0]); o.y = f2bf(acc[i][1]);
            o.z = f2bf(acc[i][2]); o.w = f2bf(acc[i][3]);
            *(ushort4*)(out16 + (size_t)r * HD + cq * 4) = o;
            out8[(size_t)r * 16 + cq] = pack_fp8x4(acc[i][0], acc[i][1], acc[i][2], acc[i][3]);
        }
    }
}

// ---------- fused aggregation: 8-edge fp8 gathers (64B/edge-row), prefetch depth 1 ----------
// lane = (g = lane>>3 edge slot 0..7, p = lane&7 h-octet). One wave per node.
__global__ __launch_bounds__(256) void agg_kernel(const int* __restrict__ csr,
                                                  const int* __restrict__ off,
                                                  const float* __restrict__ dis,
                                                  const unsigned short* __restrict__ h16,
                                                  const unsigned* __restrict__ h8,
                                                  const float* __restrict__ b,
                                                  unsigned short* __restrict__ z16, int N) {
    const int lane = threadIdx.x & 63;
    const int wid  = threadIdx.x >> 6;
    const int n = blockIdx.x * 4 + wid;
    if (n >= N) return;
    const int beg = off[n];
    const int c = min(off[n + 1] - beg, 64);
    int   s_l = 0;
    float w_l = 0.f;
    if (lane < c) {
        s_l = csr[beg + lane];
        w_l = dis[s_l];
    }
    const float dn = dis[n];
    const int g = lane >> 3;
    const int p = lane & 7;
    float a[8];
#pragma unroll
    for (int j = 0; j < 8; ++j) a[j] = 0.f;
    // prefetch edge group 0
    int   sE = __shfl(s_l, g);
    float wE = __shfl(w_l, g);
    uint2 hv = *(const uint2*)(h8 + (size_t)sE * 16 + p * 2);
    for (int e = 8; e < c; e += 8) {
        const int   sN = __shfl(s_l, e + g);
        const float wN = __shfl(w_l, e + g);
        const uint2 nv = *(const uint2*)(h8 + (size_t)sN * 16 + p * 2);
        floatx2 f01 = __builtin_amdgcn_cvt_pk_f32_fp8(hv.x, false);
        floatx2 f23 = __builtin_amdgcn_cvt_pk_f32_fp8(hv.x, true);
        floatx2 f45 = __builtin_amdgcn_cvt_pk_f32_fp8(hv.y, false);
        floatx2 f67 = __builtin_amdgcn_cvt_pk_f32_fp8(hv.y, true);
        a[0] = fmaf(f01[0], wE, a[0]); a[1] = fmaf(f01[1], wE, a[1]);
        a[2] = fmaf(f23[0], wE, a[2]); a[3] = fmaf(f23[1], wE, a[3]);
        a[4] = fmaf(f45[0], wE, a[4]); a[5] = fmaf(f45[1], wE, a[5]);
        a[6] = fmaf(f67[0], wE, a[6]); a[7] = fmaf(f67[1], wE, a[7]);
        hv = nv; wE = wN;
    }
    {
        floatx2 f01 = __builtin_amdgcn_cvt_pk_f32_fp8(hv.x, false);
        floatx2 f23 = __builtin_amdgcn_cvt_pk_f32_fp8(hv.x, true);
        floatx2 f45 = __builtin_amdgcn_cvt_pk_f32_fp8(hv.y, false);
        floatx2 f67 = __builtin_amdgcn_cvt_pk_f32_fp8(hv.y, true);
        a[0] = fmaf(f01[0], wE, a[0]); a[1] = fmaf(f01[1], wE, a[1]);
        a[2] = fmaf(f23[0], wE, a[2]); a[3] = fmaf(f23[1], wE, a[3]);
        a[4] = fmaf(f45[0], wE, a[4]); a[5] = fmaf(f45[1], wE, a[5]);
        a[6] = fmaf(f67[0], wE, a[6]); a[7] = fmaf(f67[1], wE, a[7]);
    }
#pragma unroll
    for (int st = 8; st <= 32; st <<= 1)
#pragma unroll
        for (int j = 0; j < 8; ++j) a[j] += __shfl_xor(a[j], st);
    if (g == 0) {
        const uint4 sv = *(const uint4*)(h16 + (size_t)n * HD + p * 8);
        const unsigned ss[4] = {sv.x, sv.y, sv.z, sv.w};
        const float4 b0 = *(const float4*)(b + p * 8);
        const float4 b1 = *(const float4*)(b + p * 8 + 4);
        const float bb[8] = {b0.x, b0.y, b0.z, b0.w, b1.x, b1.y, b1.z, b1.w};
        float o[8];
#pragma unroll
        for (int q = 0; q < 4; ++q) {
            o[2 * q]     = a[2 * q]     + __uint_as_float(ss[q] << 16) * dn;
            o[2 * q + 1] = a[2 * q + 1] + __uint_as_float(ss[q] & 0xFFFF0000u) * dn;
        }
#pragma unroll
        for (int j = 0; j < 8; ++j) o[j] = fmaxf(fmaf(o[j], dn, bb[j]), 0.f);
        ushort4 o0, o1;
        o0.x = f2bf(o[0]); o0.y = f2bf(o[1]); o0.z = f2bf(o[2]); o0.w = f2bf(o[3]);
        o1.x = f2bf(o[4]); o1.y = f2bf(o[5]); o1.z = f2bf(o[6]); o1.w = f2bf(o[7]);
        unsigned short* zp = z16 + (size_t)n * HD + p * 8;
        *(ushort4*)zp = o0;
        *(ushort4*)(zp + 4) = o1;
    }
}

// ---------- u/d precompute -> fp8: u8[n*64+h] (4 m-vals), d8[n*64+h] (4 l-vals) ----------
__global__ __launch_bounds__(256) void uprep_kernel(const unsigned short* __restrict__ z16,
                                                    const float* __restrict__ Wp,
                                                    unsigned* __restrict__ u8,
                                                    unsigned* __restrict__ d8, int N) {
    const int i = blockIdx.x * blockDim.x + threadIdx.x;
    const int total = N * HD;
    if (i >= total) return;
    const size_t NH = (size_t)N_NODES * HD;
    const float z0 = bf2f(z16[0 * NH + i]), z1 = bf2f(z16[1 * NH + i]);
    const float z2 = bf2f(z16[2 * NH + i]), z3 = bf2f(z16[3 * NH + i]);
    d8[i] = pack_fp8x4(z0, z1, z2, z3);
    const float u0 = z0 * Wp[0] + z1 * Wp[4] + z2 * Wp[8]  + z3 * Wp[12];
    const float u1 = z0 * Wp[1] + z1 * Wp[5] + z2 * Wp[9]  + z3 * Wp[13];
    const float u2 = z0 * Wp[2] + z1 * Wp[6] + z2 * Wp[10] + z3 * Wp[14];
    const float u3 = z0 * Wp[3] + z1 * Wp[7] + z2 * Wp[11] + z3 * Wp[15];
    u8[i] = pack_fp8x4(u0, u1, u2, u3);
}

// ---------- link prediction + BCE loss: 8 edges per wave-iter, fp8 dword gathers ----------
__global__ __launch_bounds__(256) void linkpred_kernel(const unsigned* __restrict__ u8,
                                                       const unsigned* __restrict__ d8,
                                                       const int* __restrict__ pos,
                                                       const int* __restrict__ neg,
                                                       const float* __restrict__ bp,
                                                       double* __restrict__ acc, int EP) {
    const int lane = threadIdx.x & 63;
    const int wid  = threadIdx.x >> 6;
    const float bpv = bp[0];
    int gw = blockIdx.x * 4 + wid;
    const int nw = gridDim.x * 4;
    const int nchunks = (2 * EP) >> 3;
    float lsum = 0.f;
    for (int c0 = gw; c0 < nchunks; c0 += nw) {
        const int c = __builtin_amdgcn_readfirstlane(c0);
        const int i0 = c << 3;
        const bool is_pos = i0 < EP;
        const int* __restrict__ eptr = is_pos ? pos : neg;
        const int jj0 = is_pos ? i0 : i0 - EP;
        float t[8];
#pragma unroll
        for (int k = 0; k < 8; ++k) {
            const int e0 = eptr[jj0 + k];
            const int e1 = eptr[EP + jj0 + k];
            const unsigned uv = u8[(size_t)e0 * HD + lane];
            const unsigned dv = d8[(size_t)e1 * HD + lane];
            floatx2 ua = __builtin_amdgcn_cvt_pk_f32_fp8(uv, false);
            floatx2 ub = __builtin_amdgcn_cvt_pk_f32_fp8(uv, true);
            floatx2 da = __builtin_amdgcn_cvt_pk_f32_fp8(dv, false);
            floatx2 db = __builtin_amdgcn_cvt_pk_f32_fp8(dv, true);
            float s = ua[0] * da[0];
            s = fmaf(ua[1], da[1], s);
            s = fmaf(ub[0], db[0], s);
            s = fmaf(ub[1], db[1], s);
            t[k] = s;
        }
#pragma unroll
        for (int st = 1; st <= 32; st <<= 1) {
#pragma unroll
            for (int k = 0; k < 8; ++k) t[k] += __shfl_xor(t[k], st);
        }
        if (lane < 8) {
            float tt = t[0];
            tt = (lane == 1) ? t[1] : tt;
            tt = (lane == 2) ? t[2] : tt;
            tt = (lane == 3) ? t[3] : tt;
            tt = (lane == 4) ? t[4] : tt;
            tt = (lane == 5) ? t[5] : tt;
            tt = (lane == 6) ? t[6] : tt;
            tt = (lane == 7) ? t[7] : tt;
            float logit  = tt + bpv;
            float target = (i0 + lane == EP) ? 1.f : 0.f;
            lsum += fmaxf(logit, 0.f) - logit * target + log1pf(expf(-fabsf(logit)));
        }
    }
#pragma unroll
    for (int o = 32; o >= 1; o >>= 1) lsum += __shfl_xor(lsum, o);
    __shared__ float wsum[4];
    if (lane == 0) wsum[wid] = lsum;
    __syncthreads();
    if (threadIdx.x == 0) {
        double bs = (double)wsum[0] + (double)wsum[1] + (double)wsum[2] + (double)wsum[3];
        atomicAdd(acc, bs);
    }
}

__global__ void loss_final(const double* __restrict__ acc, float* __restrict__ out, int denom) {
    out[0] = (float)(acc[0] / (double)denom);
}

extern "C" void kernel_launch(void* const* d_in, const int* in_sizes, int n_in,
                              void* d_out, int out_size, void* d_ws, size_t ws_size,
                              hipStream_t stream) {
    const float* x   = (const float*)d_in[0];
    const int*   ei  = (const int*)d_in[1];
    const int*   pos = (const int*)d_in[2];
    const int*   neg = (const int*)d_in[3];
    const float* W0  = (const float*)d_in[4];
    const float* b0  = (const float*)d_in[5];
    const float* Wh  = (const float*)d_in[6];
    const float* bh  = (const float*)d_in[7];
    const float* Wp  = (const float*)d_in[8];
    const float* bp  = (const float*)d_in[9];
    const int E  = in_sizes[1] / 2;   // 800000
    const int EP = in_sizes[2] / 2;   // 100000
    const int N  = N_NODES;
    const size_t NH = (size_t)N * HD;

    // ---- workspace layout (256B aligned) ----
    char* ws = (char*)d_ws;
    size_t off_b = 0;
    auto alloc = [&](size_t bytes) { char* p = ws + off_b; off_b = (off_b + bytes + 255) & ~(size_t)255; return p; };
    unsigned short* h16 = (unsigned short*)alloc(NH * sizeof(unsigned short));       // 6.4 MB
    unsigned*       h8  = (unsigned*)alloc(NH);                                      // 3.2 MB (1B/elem)
    unsigned short* z16 = (unsigned short*)alloc(4 * NH * sizeof(unsigned short));   // 25.6 MB
    unsigned*       u8  = (unsigned*)alloc(NH * sizeof(unsigned));                   // 12.8 MB
    unsigned*       d8  = (unsigned*)alloc(NH * sizeof(unsigned));                   // 12.8 MB
    float* dis = (float*)alloc((size_t)N * sizeof(float));                           // 200 KB
    int*   off = (int*)alloc((size_t)(N + 1) * sizeof(int));                         // 200 KB
    int*   csr = (int*)alloc((size_t)E * sizeof(int));                               // 3.2 MB
    unsigned* pk = (unsigned*)alloc((size_t)E * sizeof(unsigned));                   // 3.2 MB
    int*   bbase = (int*)alloc((size_t)(NBKT + 1) * sizeof(int));
    int*   gcur  = (int*)alloc((size_t)NBKT * sizeof(int));
    char*  zbase = ws + off_b;
    int*   bcnt = (int*)alloc((size_t)NBKT * sizeof(int));
    double* acc = (double*)alloc(sizeof(double));
    size_t zero_bytes = (size_t)((char*)acc - zbase) + sizeof(double);

    hipMemsetAsync(zbase, 0, zero_bytes, stream);

    const int* src = ei;
    const int* dst = ei + E;

    // CSR build: bucket hist -> scan -> partition -> per-bucket sort (+off, dis)
    bhist_kernel<<<(E + 2047) / 2048, 256, 0, stream>>>(dst, bcnt, E);
    bscan_kernel<<<1, 256, 0, stream>>>(bcnt, bbase, gcur);
    partition_kernel<<<(E + 8191) / 8192, 256, 0, stream>>>(src, dst, gcur, pk, E);
    bsort_kernel<<<NBKT, 256, 0, stream>>>(pk, bbase, off, dis, csr, E, N);

    const int agg_blocks  = (N + 3) / 4;
    const int gemm_blocks = (N + 63) / 64;

    // layer 0
    gemm_kernel<128, false><<<gemm_blocks, 256, 0, stream>>>(x, W0, h16, h8, N);
    agg_kernel<<<agg_blocks, 256, 0, stream>>>(csr, off, dis, h16, h8, b0, z16, N);

    // layers 1..3
    for (int l = 1; l < 4; ++l) {
        unsigned short* zprev = z16 + (size_t)(l - 1) * NH;
        unsigned short* zcur  = z16 + (size_t)l * NH;
        gemm_kernel<64, true><<<gemm_blocks, 256, 0, stream>>>(zprev, Wh + (size_t)(l - 1) * HD * HD, h16, h8, N);
        agg_kernel<<<agg_blocks, 256, 0, stream>>>(csr, off, dis, h16, h8,
                                                   bh + (size_t)(l - 1) * HD, zcur, N);
    }

    // link prediction + loss
    uprep_kernel<<<(N * HD + 255) / 256, 256, 0, stream>>>(z16, Wp, u8, d8, N);
    linkpred_kernel<<<2048, 256, 0, stream>>>(u8, d8, pos, neg, bp, acc, EP);
    loss_final<<<1, 1, 0, stream>>>(acc, (float*)d_out, 2 * EP);
}